// Round 14
// baseline (216.575 us; speedup 1.0000x reference)
//
#include <hip/hip_runtime.h>
#include <hip/hip_bf16.h>

#define T_TOK 8192
#define D_DIM 1024
#define H_DIM 768
#define E_EXP 16
#define K_TOP 2
#define TK (T_TOK * K_TOP)
#define NT128 144

typedef __bf16 bf16x8 __attribute__((ext_vector_type(8)));
typedef unsigned short u16x8 __attribute__((ext_vector_type(8)));
typedef float f32x4 __attribute__((ext_vector_type(4)));

typedef const __attribute__((address_space(1))) void* gas_t;
typedef __attribute__((address_space(3))) void* las_t;

__device__ __forceinline__ unsigned short f2b(float f) {
    __hip_bfloat16 h = __float2bfloat16(f);
    return __builtin_bit_cast(unsigned short, h);
}
__device__ __forceinline__ float b2f(unsigned short u) {
    unsigned int x = ((unsigned int)u) << 16;
    return __builtin_bit_cast(float, x);
}

// ---------------- ballot-based route (512 threads, deterministic, no atomics) ----------------
__device__ __forceinline__ void route512(
    const int* __restrict__ idx, const float* __restrict__ wts,
    int* __restrict__ offs, int* __restrict__ tiletab,
    int* __restrict__ rows, float* __restrict__ wslot, int* __restrict__ slot_of) {
    __shared__ int wcnt[8][E_EXP];
    __shared__ int wbase[8][E_EXP];
    const int tid = threadIdx.x;
    const int w = tid >> 6, lane = tid & 63;
    const unsigned long long ltmask = (1ull << lane) - 1ull;

    int cnt[E_EXP];
#pragma unroll
    for (int e = 0; e < E_EXP; ++e) cnt[e] = 0;
    for (int c = 0; c < 32; ++c) {
        const int i = (w * 32 + c) * 64 + lane;
        const int v = idx[i];
#pragma unroll
        for (int e = 0; e < E_EXP; ++e)
            cnt[e] += (int)__popcll(__ballot(v == e));
    }
#pragma unroll
    for (int e = 0; e < E_EXP; ++e)
        if (lane == e) wcnt[w][e] = cnt[e];
    __syncthreads();
    if (tid == 0) {
        int s = 0, nt = 0;
        for (int e = 0; e < E_EXP; ++e) {
            offs[e] = s;
            int tot = 0;
            for (int ww = 0; ww < 8; ++ww) { wbase[ww][e] = s + tot; tot += wcnt[ww][e]; }
            for (int m0 = 0; m0 < tot; m0 += 128) tiletab[nt++] = (e << 16) | (m0 >> 7);
            s += tot;
        }
        offs[E_EXP] = s;
        for (int i2 = nt; i2 < NT128; ++i2) tiletab[i2] = -1;
    }
    __syncthreads();
    int base[E_EXP];
    {
        int tmp = (lane < E_EXP) ? wbase[w][lane] : 0;
#pragma unroll
        for (int e = 0; e < E_EXP; ++e) base[e] = __shfl(tmp, e, 64);
    }
    for (int c = 0; c < 32; ++c) {
        const int i = (w * 32 + c) * 64 + lane;
        const int v = idx[i];
        const float wt = wts[i];
        int pos = 0;
#pragma unroll
        for (int e = 0; e < E_EXP; ++e) {
            const unsigned long long mask = __ballot(v == e);
            if (v == e) pos = base[e] + (int)__popcll(mask & ltmask);
            base[e] += (int)__popcll(mask);
        }
        rows[pos] = i >> 1;          // K_TOP == 2
        wslot[pos] = wt;
        slot_of[i] = pos;
    }
}

__global__ __launch_bounds__(512) void k_route(
    const int* __restrict__ idx, const float* __restrict__ wts,
    int* __restrict__ offs, int* __restrict__ tiletab,
    int* __restrict__ rows, float* __restrict__ wslot, int* __restrict__ slot_of) {
    route512(idx, wts, offs, tiletab, rows, wslot, slot_of);
}

// ---------------- prep: route + W1T + W2T (x-cast fused into gemm1) ----------------
#define PRB_W1 3072
#define PRB_W2 1536
#define PRB_TOT (1 + PRB_W1 + PRB_W2)

__global__ __launch_bounds__(512) void k_prepa(
    const float* __restrict__ W1, const float* __restrict__ W2,
    const int* __restrict__ idx, const float* __restrict__ wts,
    unsigned short* __restrict__ W1T, unsigned short* __restrict__ W2T,
    int* __restrict__ offs, int* __restrict__ tiletab,
    int* __restrict__ rows, float* __restrict__ wslot, int* __restrict__ slot_of) {
    const int b = blockIdx.x;
    const int tid = threadIdx.x;
    if (b == 0) {
        route512(idx, wts, offs, tiletab, rows, wslot, slot_of);
        return;
    }
    // weight transpose: 2 x 64x64 tiles per block (256 threads each), bf16 LDS staging
    __shared__ unsigned short tb[2][64][66];
    const int sub = tid >> 8, t2 = tid & 255;
    const float* src; unsigned short* dst;
    int K, C, e, kb, cb, pack;
    if (b <= PRB_W1) {
        const int q = (b - 1) * 2 + sub;
        K = D_DIM; C = 2 * H_DIM; pack = 1;
        e = q / 384; const int r = q % 384;
        kb = (r % 16) * 64; cb = (r / 16) * 64;
        src = W1; dst = W1T;
    } else {
        const int q = (b - 1 - PRB_W1) * 2 + sub;
        K = H_DIM; C = D_DIM; pack = 0;
        e = q / 192; const int r = q % 192;
        kb = (r % 12) * 64; cb = (r / 12) * 64;
        src = W2; dst = W2T;
    }
    const float* s = src + ((size_t)e * K + kb) * C + cb;
#pragma unroll
    for (int i = 0; i < 4; ++i) {
        const int kk = (t2 >> 4) + i * 16, c4 = (t2 & 15) * 4;
        const float4 v = *reinterpret_cast<const float4*>(&s[(size_t)kk * C + c4]);
        ushort4 u;
        u.x = f2b(v.x); u.y = f2b(v.y); u.z = f2b(v.z); u.w = f2b(v.w);
        *reinterpret_cast<ushort4*>(&tb[sub][kk][c4]) = u;
    }
    __syncthreads();
#pragma unroll
    for (int i = 0; i < 2; ++i) {
        const int cc = (t2 >> 3) + i * 32;
        const int k8 = (t2 & 7) * 8;
        const int j = cb + cc;
        int drow;
        if (pack) drow = (j < H_DIM) ? ((j >> 5) * 64 + (j & 31))
                                     : (((j - H_DIM) >> 5) * 64 + 32 + ((j - H_DIM) & 31));
        else drow = j;
        u16x8 u;
#pragma unroll
        for (int q8 = 0; q8 < 8; ++q8) u[q8] = tb[sub][k8 + q8][cc];
        *reinterpret_cast<u16x8*>(&dst[((size_t)e * C + drow) * K + kb + k8]) = u;
    }
}

// ================= gemm1: A staged from fp32 x in-kernel (T14 issue-early/write-late) =================
// BM=128, BK=32, 48 KiB dbuf, 2 blocks/CU. Per K-step:
//   top: issue A(t+2) reg loads (latency hides under MFMA)
//   ds_read frags[c]; 16 MFMA; lgkmcnt(0); barrier R (reads of [c] done)
//   stageB(t+2)->SB[c]; vmcnt(2) (A(t+2)+B(t+1) done, B(t+2) stays in flight);
//   cvt+ds_write A(t+2)->SA[c]; lgkmcnt(0); barrier P (publishes tile t+1)
// Write swizzle: phys chunk = aj ^ ((row>>1)&3) == read-side rk. <=2-way banks.

__global__ __launch_bounds__(512, 2) void k_gemm1_fast(
    const float* __restrict__ x, const unsigned short* __restrict__ W1T,
    const int* __restrict__ offs, const int* __restrict__ tiletab,
    const int* __restrict__ rows, unsigned short* __restrict__ act) {
    const int ti = (blockIdx.x & 7) * (NT128 / 8) + (blockIdx.x >> 3);  // XCD swizzle
    const int tt = tiletab[ti];
    if (tt < 0) return;
    const int e = tt >> 16, m0 = (tt & 0xffff) << 7;
    const int off = offs[e], n_e = offs[e + 1] - off;
    const int by = blockIdx.y;   // 0..5

    __shared__ unsigned short SA[2][128 * 32];   // 16 KiB
    __shared__ unsigned short SB[2][256 * 32];   // 32 KiB

    const int tid = threadIdx.x;
    const int wid = tid >> 6, lane = tid & 63;
    const int l15 = lane & 15, kq = lane >> 4;
    const int wm = wid >> 2, wn = wid & 3;
    const int srow = tid >> 2;                       // A row / B staging row
    const int aj = tid & 3;                          // A logical k-chunk
    const int aphys = aj ^ ((tid >> 3) & 3);         // A phys k-chunk (matches rk)
    const int esw = (((tid & 3) ^ ((tid >> 3) & 3)) << 3);   // B pre-swizzled src elem off
    const int rk = ((kq ^ ((l15 >> 1) & 3)) << 3);

    int tok;
    { int s = m0 + srow; s = (s < n_e) ? s : (n_e - 1); tok = rows[off + s]; }
    const float* xrow = x + (size_t)tok * D_DIM + aj * 8;
    size_t bB[2];
#pragma unroll
    for (int j = 0; j < 2; ++j)
        bB[j] = ((size_t)e * (2 * H_DIM) + by * 256 + j * 128 + srow) * D_DIM + esw;

    f32x4 acc[4][4];
#pragma unroll
    for (int m = 0; m < 4; ++m)
#pragma unroll
        for (int n = 0; n < 4; ++n)
#pragma unroll
            for (int r = 0; r < 4; ++r) acc[m][n][r] = 0.f;

    auto stageB = [&](int buf, int k0) {
#pragma unroll
        for (int j = 0; j < 2; ++j) {
            const unsigned short* gb = W1T + bB[j] + k0;
            __builtin_amdgcn_global_load_lds((gas_t)gb,
                (las_t)((char*)&SB[buf][0] + j * 8192 + tid * 16), 16, 0, 0);
        }
    };
    auto writeA = [&](int buf, const float4& v0, const float4& v1) {
        u16x8 u;
        u[0] = f2b(v0.x); u[1] = f2b(v0.y); u[2] = f2b(v0.z); u[3] = f2b(v0.w);
        u[4] = f2b(v1.x); u[5] = f2b(v1.y); u[6] = f2b(v1.z); u[7] = f2b(v1.w);
        *reinterpret_cast<u16x8*>(&SA[buf][srow * 32 + aphys * 8]) = u;
    };

    // prologue: tiles 0 and 1
    float4 pa0, pa1, qa0, qa1;
    pa0 = *reinterpret_cast<const float4*>(xrow + 0);
    pa1 = *reinterpret_cast<const float4*>(xrow + 4);
    stageB(0, 0);
    qa0 = *reinterpret_cast<const float4*>(xrow + 32);
    qa1 = *reinterpret_cast<const float4*>(xrow + 36);
    stageB(1, 32);
    asm volatile("s_waitcnt vmcnt(0)" ::: "memory");
    writeA(0, pa0, pa1);
    writeA(1, qa0, qa1);
    asm volatile("s_waitcnt lgkmcnt(0)" ::: "memory");
    __builtin_amdgcn_s_barrier();
    asm volatile("" ::: "memory");

    int c = 0;
    const int NT = D_DIM / 32;   // 32
    for (int t = 0; t < NT; ++t) {
        const bool st = (t + 2 < NT);
        if (st) {   // issue-early A loads for tile t+2
            pa0 = *reinterpret_cast<const float4*>(xrow + (t + 2) * 32);
            pa1 = *reinterpret_cast<const float4*>(xrow + (t + 2) * 32 + 4);
        }
        bf16x8 a[4], b[4];
#pragma unroll
        for (int m = 0; m < 4; ++m) {
            const int row = wm * 64 + m * 16 + l15;
            a[m] = __builtin_bit_cast(bf16x8, *reinterpret_cast<const u16x8*>(
                &SA[c][row * 32 + rk]));
        }
#pragma unroll
        for (int n = 0; n < 4; ++n) {
            const int row = wn * 64 + n * 16 + l15;
            b[n] = __builtin_bit_cast(bf16x8, *reinterpret_cast<const u16x8*>(
                &SB[c][row * 32 + rk]));
        }
#pragma unroll
        for (int m = 0; m < 4; ++m)
#pragma unroll
            for (int n = 0; n < 4; ++n)
                acc[m][n] = __builtin_amdgcn_mfma_f32_16x16x32_bf16(a[m], b[n], acc[m][n], 0, 0, 0);
        asm volatile("s_waitcnt lgkmcnt(0)" ::: "memory");
        __builtin_amdgcn_s_barrier();              // barrier R
        asm volatile("" ::: "memory");
        if (st) {
            stageB(c, (t + 2) * 32);
            asm volatile("s_waitcnt vmcnt(2)" ::: "memory");
            writeA(c, pa0, pa1);
            asm volatile("s_waitcnt lgkmcnt(0)" ::: "memory");
        } else if (t + 1 < NT) {
            asm volatile("s_waitcnt vmcnt(0)" ::: "memory");
        }
        __builtin_amdgcn_s_barrier();              // barrier P
        asm volatile("" ::: "memory");
        c ^= 1;
    }
    // epilogue: silu-gate; frag n<2 = v-cols, n>=2 = paired g-cols
#pragma unroll
    for (int m = 0; m < 4; ++m)
#pragma unroll
        for (int r = 0; r < 4; ++r) {
            const int row = wm * 64 + m * 16 + kq * 4 + r;
            if (m0 + row < n_e) {
#pragma unroll
                for (int nv = 0; nv < 2; ++nv) {
                    const int col = by * 128 + wn * 32 + nv * 16 + l15;
                    const float vv = acc[m][nv][r], gg = acc[m][2 + nv][r];
                    const float s = gg / (1.0f + __expf(-gg));
                    act[(size_t)(off + m0 + row) * H_DIM + col] = f2b(vv * s);
                }
            }
        }
}

// gemm2: unchanged r12 structure (bf16 operands, depth-2 counted vmcnt)
__global__ __launch_bounds__(512, 2) void k_gemm2_fast(
    const unsigned short* __restrict__ act, const unsigned short* __restrict__ W2T,
    const int* __restrict__ offs, const int* __restrict__ tiletab,
    const float* __restrict__ wslot, unsigned short* __restrict__ slot_out) {
    const int ti = (blockIdx.x & 7) * (NT128 / 8) + (blockIdx.x >> 3);
    const int tt = tiletab[ti];
    if (tt < 0) return;
    const int e = tt >> 16, m0 = (tt & 0xffff) << 7;
    const int off = offs[e], n_e = offs[e + 1] - off;
    const int by = blockIdx.y;   // 0..3

    __shared__ unsigned short SA[2][128 * 32];
    __shared__ unsigned short SB[2][256 * 32];

    const int tid = threadIdx.x;
    const int wid = tid >> 6, lane = tid & 63;
    const int l15 = lane & 15, kq = lane >> 4;
    const int wm = wid >> 2, wn = wid & 3;
    const int srow = tid >> 2;
    const int esw = (((tid & 3) ^ ((tid >> 3) & 3)) << 3);
    const int rk = ((kq ^ ((l15 >> 1) & 3)) << 3);

    int slotA;
    { int s = m0 + srow; s = (s < n_e) ? s : (n_e - 1); slotA = off + s; }
    size_t bB[2];
#pragma unroll
    for (int j = 0; j < 2; ++j)
        bB[j] = ((size_t)e * D_DIM + by * 256 + j * 128 + srow) * H_DIM + esw;

    f32x4 acc[4][4];
#pragma unroll
    for (int m = 0; m < 4; ++m)
#pragma unroll
        for (int n = 0; n < 4; ++n)
#pragma unroll
            for (int r = 0; r < 4; ++r) acc[m][n][r] = 0.f;

    auto stage = [&](int buf, int k0) {
        const unsigned short* ga = act + (size_t)slotA * H_DIM + k0 + esw;
        __builtin_amdgcn_global_load_lds((gas_t)ga,
            (las_t)((char*)&SA[buf][0] + tid * 16), 16, 0, 0);
#pragma unroll
        for (int j = 0; j < 2; ++j) {
            const unsigned short* gb = W2T + bB[j] + k0;
            __builtin_amdgcn_global_load_lds((gas_t)gb,
                (las_t)((char*)&SB[buf][0] + j * 8192 + tid * 16), 16, 0, 0);
        }
    };

    stage(0, 0);
    stage(1, 32);
    int c = 0;
    const int NT = H_DIM / 32;   // 24
    for (int t = 0; t < NT; ++t) {
        if (t < NT - 1) asm volatile("s_waitcnt vmcnt(3)" ::: "memory");
        else            asm volatile("s_waitcnt vmcnt(0)" ::: "memory");
        __builtin_amdgcn_s_barrier();
        asm volatile("" ::: "memory");
        bf16x8 a[4], b[4];
#pragma unroll
        for (int m = 0; m < 4; ++m) {
            const int row = wm * 64 + m * 16 + l15;
            a[m] = __builtin_bit_cast(bf16x8, *reinterpret_cast<const u16x8*>(
                &SA[c][row * 32 + rk]));
        }
#pragma unroll
        for (int n = 0; n < 4; ++n) {
            const int row = wn * 64 + n * 16 + l15;
            b[n] = __builtin_bit_cast(bf16x8, *reinterpret_cast<const u16x8*>(
                &SB[c][row * 32 + rk]));
        }
#pragma unroll
        for (int m = 0; m < 4; ++m)
#pragma unroll
            for (int n = 0; n < 4; ++n)
                acc[m][n] = __builtin_amdgcn_mfma_f32_16x16x32_bf16(a[m], b[n], acc[m][n], 0, 0, 0);
        asm volatile("s_waitcnt lgkmcnt(0)" ::: "memory");
        __builtin_amdgcn_s_barrier();
        asm volatile("" ::: "memory");
        if (t + 2 < NT) stage(c, (t + 2) * 32);
        c ^= 1;
    }
#pragma unroll
    for (int m = 0; m < 4; ++m)
#pragma unroll
        for (int r = 0; r < 4; ++r) {
            const int row = wm * 64 + m * 16 + kq * 4 + r;
            if (m0 + row < n_e) {
                const int slot = off + m0 + row;
                const float w = wslot[slot];
#pragma unroll
                for (int n = 0; n < 4; ++n) {
                    const int col = by * 256 + wn * 64 + n * 16 + l15;
                    slot_out[(size_t)slot * D_DIM + col] = f2b(w * acc[m][n][r]);
                }
            }
        }
}

// ================= FALLBACK PATH (small ws) =================
__global__ __launch_bounds__(256) void k_gather(const float* __restrict__ x,
                                                const int* __restrict__ rows,
                                                unsigned short* __restrict__ xg) {
    const int s = blockIdx.x, t = threadIdx.x;
    const int tok = rows[s];
    const float4 v = *reinterpret_cast<const float4*>(&x[(size_t)tok * D_DIM + t * 4]);
    ushort4 u;
    u.x = f2b(v.x); u.y = f2b(v.y); u.z = f2b(v.z); u.w = f2b(v.w);
    *reinterpret_cast<ushort4*>(&xg[(size_t)s * D_DIM + t * 4]) = u;
}

__global__ __launch_bounds__(256) void k_gemm1_fb(
    const unsigned short* __restrict__ xg, const float* __restrict__ W1,
    const int* __restrict__ offs, const int* __restrict__ tiletab,
    unsigned short* __restrict__ act) {
    const int tt = tiletab[blockIdx.x];
    if (tt < 0) return;
    const int e = tt >> 16, m0 = (tt & 0xffff) << 7;
    const int off = offs[e], n_e = offs[e + 1] - off;
    const int h0 = blockIdx.y * 64;

    __shared__ unsigned short Ab[128 * 64];
    __shared__ unsigned short Bb[128 * 66];

    const int tid = threadIdx.x;
    const int wid = tid >> 6, lane = tid & 63;
    const int l15 = lane & 15, kq = lane >> 4;

    f32x4 acc[2][8];
#pragma unroll
    for (int m = 0; m < 2; ++m)
#pragma unroll
        for (int n = 0; n < 8; ++n)
#pragma unroll
            for (int r = 0; r < 4; ++r) acc[m][n][r] = 0.f;

    for (int k0 = 0; k0 < D_DIM; k0 += 64) {
        __syncthreads();
#pragma unroll
        for (int j = 0; j < 4; ++j) {
            const int o = wid * 4096 + j * 1024 + lane * 16;
            const int row = o >> 7, kb = o & 127;
            int gr = off + m0 + row; gr = (gr < TK) ? gr : (TK - 1);
            const unsigned short* gp = xg + (size_t)gr * D_DIM + k0 + (kb >> 1);
            __builtin_amdgcn_global_load_lds((gas_t)gp,
                (las_t)((char*)Ab + wid * 4096 + j * 1024), 16, 0, 0);
        }
        {
            const float* W1e = W1 + (size_t)e * D_DIM * (2 * H_DIM);
#pragma unroll
            for (int i = 0; i < 8; ++i) {
                const int flat = tid + 256 * i;
                const int cg = flat & 31, kk = flat >> 5;
                const int cc = cg * 4;
                const int gc = (cc < 64) ? (h0 + cc) : (H_DIM + h0 + cc - 64);
                const float4 v = *reinterpret_cast<const float4*>(
                    &W1e[(size_t)(k0 + kk) * (2 * H_DIM) + gc]);
                Bb[(cc + 0) * 66 + kk] = f2b(v.x);
                Bb[(cc + 1) * 66 + kk] = f2b(v.y);
                Bb[(cc + 2) * 66 + kk] = f2b(v.z);
                Bb[(cc + 3) * 66 + kk] = f2b(v.w);
            }
        }
        __syncthreads();
#pragma unroll
        for (int ks = 0; ks < 2; ++ks) {
            bf16x8 a[2], b[8];
#pragma unroll
            for (int m = 0; m < 2; ++m)
                a[m] = __builtin_bit_cast(bf16x8, *reinterpret_cast<const u16x8*>(
                    &Ab[(wid * 32 + m * 16 + l15) * 64 + ks * 32 + kq * 8]));
#pragma unroll
            for (int n = 0; n < 8; ++n)
                b[n] = __builtin_bit_cast(bf16x8, *reinterpret_cast<const u16x8*>(
                    &Bb[(n * 16 + l15) * 66 + ks * 32 + kq * 8]));
#pragma unroll
            for (int m = 0; m < 2; ++m)
#pragma unroll
                for (int n = 0; n < 8; ++n)
                    acc[m][n] = __builtin_amdgcn_mfma_f32_16x16x32_bf16(a[m], b[n], acc[m][n], 0, 0, 0);
        }
    }
#pragma unroll
    for (int m = 0; m < 2; ++m)
#pragma unroll
        for (int n = 0; n < 4; ++n)
#pragma unroll
            for (int r = 0; r < 4; ++r) {
                const int row = wid * 32 + m * 16 + kq * 4 + r;
                if (m0 + row < n_e) {
                    const float vv = acc[m][n][r], gg = acc[m][n + 4][r];
                    const float s = gg / (1.0f + __expf(-gg));
                    act[(size_t)(off + m0 + row) * H_DIM + h0 + n * 16 + l15] = f2b(vv * s);
                }
            }
}

__global__ __launch_bounds__(256) void k_gemm2_fb(
    const unsigned short* __restrict__ act, const float* __restrict__ W2,
    const int* __restrict__ offs, const int* __restrict__ tiletab,
    const float* __restrict__ wslot, unsigned short* __restrict__ slot_out,
    float* __restrict__ y, const int* __restrict__ rows, int atomic_mode) {
    const int tt = tiletab[blockIdx.x];
    if (tt < 0) return;
    const int e = tt >> 16, m0 = (tt & 0xffff) << 7;
    const int off = offs[e], n_e = offs[e + 1] - off;
    const int n0 = blockIdx.y * 64;

    __shared__ unsigned short Ab[128 * 64];
    __shared__ unsigned short Bb[64 * 66];

    const int tid = threadIdx.x;
    const int wid = tid >> 6, lane = tid & 63;
    const int l15 = lane & 15, kq = lane >> 4;

    f32x4 acc[2][4];
#pragma unroll
    for (int m = 0; m < 2; ++m)
#pragma unroll
        for (int n = 0; n < 4; ++n)
#pragma unroll
            for (int r = 0; r < 4; ++r) acc[m][n][r] = 0.f;

    for (int k0 = 0; k0 < H_DIM; k0 += 64) {
        __syncthreads();
#pragma unroll
        for (int j = 0; j < 4; ++j) {
            const int o = wid * 4096 + j * 1024 + lane * 16;
            const int row = o >> 7, kb = o & 127;
            int gr = off + m0 + row; gr = (gr < TK) ? gr : (TK - 1);
            const unsigned short* gp = act + (size_t)gr * H_DIM + k0 + (kb >> 1);
            __builtin_amdgcn_global_load_lds((gas_t)gp,
                (las_t)((char*)Ab + wid * 4096 + j * 1024), 16, 0, 0);
        }
        {
            const float* W2e = W2 + (size_t)e * H_DIM * D_DIM;
#pragma unroll
            for (int i = 0; i < 4; ++i) {
                const int flat = tid + 256 * i;
                const int cg = flat & 15, kk = flat >> 4;
                const int cc = cg * 4;
                const float4 v = *reinterpret_cast<const float4*>(
                    &W2e[(size_t)(k0 + kk) * D_DIM + n0 + cc]);
                Bb[(cc + 0) * 66 + kk] = f2b(v.x);
                Bb[(cc + 1) * 66 + kk] = f2b(v.y);
                Bb[(cc + 2) * 66 + kk] = f2b(v.z);
                Bb[(cc + 3) * 66 + kk] = f2b(v.w);
            }
        }
        __syncthreads();
#pragma unroll
        for (int ks = 0; ks < 2; ++ks) {
            bf16x8 a[2], b[4];
#pragma unroll
            for (int m = 0; m < 2; ++m)
                a[m] = __builtin_bit_cast(bf16x8, *reinterpret_cast<const u16x8*>(
                    &Ab[(wid * 32 + m * 16 + l15) * 64 + ks * 32 + kq * 8]));
#pragma unroll
            for (int n = 0; n < 4; ++n)
                b[n] = __builtin_bit_cast(bf16x8, *reinterpret_cast<const u16x8*>(
                    &Bb[(n * 16 + l15) * 66 + ks * 32 + kq * 8]));
#pragma unroll
            for (int m = 0; m < 2; ++m)
#pragma unroll
                for (int n = 0; n < 4; ++n)
                    acc[m][n] = __builtin_amdgcn_mfma_f32_16x16x32_bf16(a[m], b[n], acc[m][n], 0, 0, 0);
        }
    }
#pragma unroll
    for (int m = 0; m < 2; ++m)
#pragma unroll
        for (int r = 0; r < 4; ++r) {
            const int row = wid * 32 + m * 16 + kq * 4 + r;
            if (m0 + row < n_e) {
                const int slot = off + m0 + row;
                const float w = wslot[slot];
#pragma unroll
                for (int n = 0; n < 4; ++n) {
                    const float o = w * acc[m][n][r];
                    if (atomic_mode)
                        atomicAdd(&y[(size_t)rows[slot] * D_DIM + n0 + n * 16 + l15], o);
                    else
                        slot_out[(size_t)slot * D_DIM + n0 + n * 16 + l15] = f2b(o);
                }
            }
        }
}

// ---------------- combine: y[t] = out[slot(t,0)] + out[slot(t,1)] ----------------
__global__ __launch_bounds__(128) void k_combine(
    const unsigned short* __restrict__ slot_out, const int* __restrict__ slot_of,
    float* __restrict__ y) {
    const int t = blockIdx.x;
    const int d = threadIdx.x * 8;
    const int s0 = slot_of[2 * t], s1 = slot_of[2 * t + 1];
    const u16x8 a = *reinterpret_cast<const u16x8*>(&slot_out[(size_t)s0 * D_DIM + d]);
    const u16x8 b = *reinterpret_cast<const u16x8*>(&slot_out[(size_t)s1 * D_DIM + d]);
    float4 r0, r1;
    r0.x = b2f(a[0]) + b2f(b[0]); r0.y = b2f(a[1]) + b2f(b[1]);
    r0.z = b2f(a[2]) + b2f(b[2]); r0.w = b2f(a[3]) + b2f(b[3]);
    r1.x = b2f(a[4]) + b2f(b[4]); r1.y = b2f(a[5]) + b2f(b[5]);
    r1.z = b2f(a[6]) + b2f(b[6]); r1.w = b2f(a[7]) + b2f(b[7]);
    *reinterpret_cast<float4*>(&y[(size_t)t * D_DIM + d]) = r0;
    *reinterpret_cast<float4*>(&y[(size_t)t * D_DIM + d + 4]) = r1;
}

extern "C" void kernel_launch(void* const* d_in, const int* in_sizes, int n_in,
                              void* d_out, int out_size, void* d_ws, size_t ws_size,
                              hipStream_t stream) {
    const float* x = (const float*)d_in[0];
    const float* wts = (const float*)d_in[1];
    const int* idx = (const int*)d_in[2];
    const float* W1 = (const float*)d_in[4];
    const float* W2 = (const float*)d_in[5];
    float* y = (float*)d_out;

    char* ws = (char*)d_ws;
    int* offs = (int*)(ws + 128);
    int* tiletab = (int*)(ws + 320);
    int* rows = (int*)(ws + 2048);
    float* wslot = (float*)(ws + 2048 + (size_t)TK * 4);
    int* slot_of = (int*)(ws + 2048 + (size_t)TK * 8);
    const size_t OFF_XG = 2048 + (size_t)TK * 12;
    unsigned short* xg = (unsigned short*)(ws + OFF_XG);   // fallback only
    const size_t OFF_ACT = OFF_XG + (size_t)TK * D_DIM * 2;
    unsigned short* act = (unsigned short*)(ws + OFF_ACT);
    const size_t OFF_SO = OFF_ACT + (size_t)TK * H_DIM * 2;
    unsigned short* slot_out = (unsigned short*)(ws + OFF_SO);
    const size_t MID_END = OFF_SO + (size_t)TK * D_DIM * 2;
    const size_t OFF_W1T = MID_END;
    unsigned short* W1T = (unsigned short*)(ws + OFF_W1T);
    const size_t OFF_W2T = OFF_W1T + (size_t)E_EXP * 2 * H_DIM * D_DIM * 2;
    unsigned short* W2T = (unsigned short*)(ws + OFF_W2T);
    const size_t FULL_END = OFF_W2T + (size_t)E_EXP * D_DIM * H_DIM * 2;

    const int full = (ws_size >= FULL_END) ? 1 : 0;
    const int atomic_mode = (!full && ws_size < MID_END) ? 1 : 0;

    if (full) {
        k_prepa<<<PRB_TOT, 512, 0, stream>>>(W1, W2, idx, wts, W1T, W2T,
                                             offs, tiletab, rows, wslot, slot_of);
        dim3 g1(NT128, H_DIM / 128);
        k_gemm1_fast<<<g1, 512, 0, stream>>>(x, W1T, offs, tiletab, rows, act);
        dim3 g2(NT128, D_DIM / 256);
        k_gemm2_fast<<<g2, 512, 0, stream>>>(act, W2T, offs, tiletab, wslot, slot_out);
        k_combine<<<T_TOK, 128, 0, stream>>>(slot_out, slot_of, y);
    } else {
        k_route<<<1, 512, 0, stream>>>(idx, wts, offs, tiletab, rows, wslot, slot_of);
        k_gather<<<TK, 256, 0, stream>>>(x, rows, xg);
        dim3 g1(NT128, H_DIM / 64);
        k_gemm1_fb<<<g1, 256, 0, stream>>>(xg, W1, offs, tiletab, act);
        if (atomic_mode) hipMemsetAsync(y, 0, (size_t)out_size * 4, stream);
        dim3 g2(NT128, D_DIM / 64);
        k_gemm2_fb<<<g2, 256, 0, stream>>>(act, W2, offs, tiletab, wslot, slot_out, y, rows, atomic_mode);
        if (!atomic_mode)
            k_combine<<<T_TOK, 128, 0, stream>>>(slot_out, slot_of, y);
    }
}

// Round 15
// 205.020 us; speedup vs baseline: 1.0564x; 1.0564x over previous
//
#include <hip/hip_runtime.h>
#include <hip/hip_bf16.h>

#define T_TOK 8192
#define D_DIM 1024
#define H_DIM 768
#define E_EXP 16
#define K_TOP 2
#define TK (T_TOK * K_TOP)
#define NT128 144

typedef __bf16 bf16x8 __attribute__((ext_vector_type(8)));
typedef unsigned short u16x8 __attribute__((ext_vector_type(8)));
typedef float f32x4 __attribute__((ext_vector_type(4)));

typedef const __attribute__((address_space(1))) void* gas_t;
typedef __attribute__((address_space(3))) void* las_t;

__device__ __forceinline__ unsigned short f2b(float f) {
    __hip_bfloat16 h = __float2bfloat16(f);
    return __builtin_bit_cast(unsigned short, h);
}
__device__ __forceinline__ float b2f(unsigned short u) {
    unsigned int x = ((unsigned int)u) << 16;
    return __builtin_bit_cast(float, x);
}

// ---------------- ballot-based route (512 threads, deterministic, no atomics) ----------------
__device__ __forceinline__ void route512(
    const int* __restrict__ idx, const float* __restrict__ wts,
    int* __restrict__ offs, int* __restrict__ tiletab,
    int* __restrict__ rows, float* __restrict__ wslot, int* __restrict__ slot_of) {
    __shared__ int wcnt[8][E_EXP];
    __shared__ int wbase[8][E_EXP];
    const int tid = threadIdx.x;
    const int w = tid >> 6, lane = tid & 63;
    const unsigned long long ltmask = (1ull << lane) - 1ull;

    int cnt[E_EXP];
#pragma unroll
    for (int e = 0; e < E_EXP; ++e) cnt[e] = 0;
    for (int c = 0; c < 32; ++c) {
        const int i = (w * 32 + c) * 64 + lane;
        const int v = idx[i];
#pragma unroll
        for (int e = 0; e < E_EXP; ++e)
            cnt[e] += (int)__popcll(__ballot(v == e));
    }
#pragma unroll
    for (int e = 0; e < E_EXP; ++e)
        if (lane == e) wcnt[w][e] = cnt[e];
    __syncthreads();
    if (tid == 0) {
        int s = 0, nt = 0;
        for (int e = 0; e < E_EXP; ++e) {
            offs[e] = s;
            int tot = 0;
            for (int ww = 0; ww < 8; ++ww) { wbase[ww][e] = s + tot; tot += wcnt[ww][e]; }
            for (int m0 = 0; m0 < tot; m0 += 128) tiletab[nt++] = (e << 16) | (m0 >> 7);
            s += tot;
        }
        offs[E_EXP] = s;
        for (int i2 = nt; i2 < NT128; ++i2) tiletab[i2] = -1;
    }
    __syncthreads();
    int base[E_EXP];
    {
        int tmp = (lane < E_EXP) ? wbase[w][lane] : 0;
#pragma unroll
        for (int e = 0; e < E_EXP; ++e) base[e] = __shfl(tmp, e, 64);
    }
    for (int c = 0; c < 32; ++c) {
        const int i = (w * 32 + c) * 64 + lane;
        const int v = idx[i];
        const float wt = wts[i];
        int pos = 0;
#pragma unroll
        for (int e = 0; e < E_EXP; ++e) {
            const unsigned long long mask = __ballot(v == e);
            if (v == e) pos = base[e] + (int)__popcll(mask & ltmask);
            base[e] += (int)__popcll(mask);
        }
        rows[pos] = i >> 1;          // K_TOP == 2
        wslot[pos] = wt;
        slot_of[i] = pos;
    }
}

__global__ __launch_bounds__(512) void k_route(
    const int* __restrict__ idx, const float* __restrict__ wts,
    int* __restrict__ offs, int* __restrict__ tiletab,
    int* __restrict__ rows, float* __restrict__ wslot, int* __restrict__ slot_of) {
    route512(idx, wts, offs, tiletab, rows, wslot, slot_of);
}

// ---------------- fused route + prep (full path) ----------------
// block 0: ballot route. blocks [1, 2048]: x-cast. blocks [2049, 5120]: W1T;
// [5121, 6656]: W2T -- 2 tiles/block, IN-REGISTER 4x4 transpose:
// phase A: 4 coalesced float4 loads (4k x 4c), cvt, reg-transpose, 4x ushort4
//   LDS writes into XOR-swizzled [c][k] tile (phys 8B-slot = (k>>2) ^ (((c>>2)&7)<<1));
// phase B: ONE ds_read_b128 per iter (conflict-free: 8 lanes = 8 distinct swizzled
//   chunks of one row) + coalesced 16B store (8 lanes = full 128B output row).
// Replaces r12's 16 scalar ds_read_u16/thread column gather.
#define PRB_X 2048
#define PRB_W1 3072
#define PRB_W2 1536
#define PRB_TOT (1 + PRB_X + PRB_W1 + PRB_W2)

__global__ __launch_bounds__(512) void k_preproute(
    const float* __restrict__ x, const float* __restrict__ W1, const float* __restrict__ W2,
    const int* __restrict__ idx, const float* __restrict__ wts,
    unsigned short* __restrict__ xb, unsigned short* __restrict__ W1T,
    unsigned short* __restrict__ W2T,
    int* __restrict__ offs, int* __restrict__ tiletab,
    int* __restrict__ rows, float* __restrict__ wslot, int* __restrict__ slot_of) {
    const int b = blockIdx.x;
    const int tid = threadIdx.x;
    if (b == 0) {
        route512(idx, wts, offs, tiletab, rows, wslot, slot_of);
        return;
    }
    if (b <= PRB_X) {   // x-cast: 4 rows (4096 elems) per block
        const size_t base = (size_t)(b - 1) * 4096 + (size_t)tid * 8;
        const float4 v0 = *reinterpret_cast<const float4*>(&x[base]);
        const float4 v1 = *reinterpret_cast<const float4*>(&x[base + 4]);
        u16x8 u;
        u[0] = f2b(v0.x); u[1] = f2b(v0.y); u[2] = f2b(v0.z); u[3] = f2b(v0.w);
        u[4] = f2b(v1.x); u[5] = f2b(v1.y); u[6] = f2b(v1.z); u[7] = f2b(v1.w);
        *reinterpret_cast<u16x8*>(&xb[base]) = u;
        return;
    }
    // ---- weight transpose: 2 x 64x64 tiles per block (256 threads each) ----
    __shared__ unsigned short tb[2][64 * 64];   // 8 KiB per tile, swizzled [c][k]
    const int sub = tid >> 8, t2 = tid & 255;
    const float* src; unsigned short* dst;
    int K, C, e, kb, cb, pack;
    if (b <= PRB_X + PRB_W1) {
        const int q = (b - 1 - PRB_X) * 2 + sub;
        K = D_DIM; C = 2 * H_DIM; pack = 1;
        e = q / 384; const int r = q % 384;
        kb = (r % 16) * 64; cb = (r / 16) * 64;
        src = W1; dst = W1T;
    } else {
        const int q = (b - 1 - PRB_X - PRB_W1) * 2 + sub;
        K = H_DIM; C = D_DIM; pack = 0;
        e = q / 192; const int r = q % 192;
        kb = (r % 12) * 64; cb = (r / 12) * 64;
        src = W2; dst = W2T;
    }
    // phase A: 4(k) x 4(c) fp32 block -> reg transpose -> swizzled LDS
    {
        const int c4 = (t2 & 15) * 4, k4 = (t2 >> 4) * 4;
        const float* s = src + ((size_t)e * K + kb + k4) * C + cb + c4;
        float4 v0 = *reinterpret_cast<const float4*>(&s[0 * C]);
        float4 v1 = *reinterpret_cast<const float4*>(&s[1 * C]);
        float4 v2 = *reinterpret_cast<const float4*>(&s[2 * C]);
        float4 v3 = *reinterpret_cast<const float4*>(&s[3 * C]);
        const float cols[4][4] = {{v0.x, v1.x, v2.x, v3.x},
                                  {v0.y, v1.y, v2.y, v3.y},
                                  {v0.z, v1.z, v2.z, v3.z},
                                  {v0.w, v1.w, v2.w, v3.w}};
        const int s0 = k4 >> 2;
        const int xsw = ((c4 >> 2) & 7) << 1;   // same for ci=0..3 (c4 mult of 4)
#pragma unroll
        for (int ci = 0; ci < 4; ++ci) {
            const int c = c4 + ci;
            ushort4 w;
            w.x = f2b(cols[ci][0]); w.y = f2b(cols[ci][1]);
            w.z = f2b(cols[ci][2]); w.w = f2b(cols[ci][3]);
            *reinterpret_cast<ushort4*>(
                (char*)&tb[sub][0] + c * 128 + (s0 ^ xsw) * 8) = w;
        }
    }
    __syncthreads();
    // phase B: vectorized swizzled read + coalesced store
#pragma unroll
    for (int i = 0; i < 2; ++i) {
        const int c = (t2 >> 3) + i * 32;   // 0..63
        const int j = t2 & 7;               // 16B chunk (logical slots 2j, 2j+1)
        const int xsw = ((c >> 2) & 7) << 1;
        const u16x8 u = *reinterpret_cast<const u16x8*>(
            (char*)&tb[sub][0] + c * 128 + ((2 * j) ^ xsw) * 8);
        const int jc = cb + c;
        int drow;
        if (pack) drow = (jc < H_DIM) ? ((jc >> 5) * 64 + (jc & 31))
                                      : (((jc - H_DIM) >> 5) * 64 + 32 + ((jc - H_DIM) & 31));
        else drow = jc;
        *reinterpret_cast<u16x8*>(&dst[((size_t)e * C + drow) * K + kb + j * 8]) = u;
    }
}

// ================= FAST PATH: BM=128, BK=32, 48 KiB dbuf, counted vmcnt =================
// (r7/r8/r12 proven: 2 blocks/CU, depth-2 prefetch, vmcnt(3), 0-conflict swizzle)

__global__ __launch_bounds__(512, 2) void k_gemm1_fast(
    const unsigned short* __restrict__ xb, const unsigned short* __restrict__ W1T,
    const int* __restrict__ offs, const int* __restrict__ tiletab,
    const int* __restrict__ rows, unsigned short* __restrict__ act) {
    const int ti = (blockIdx.x & 7) * (NT128 / 8) + (blockIdx.x >> 3);  // XCD swizzle
    const int tt = tiletab[ti];
    if (tt < 0) return;
    const int e = tt >> 16, m0 = (tt & 0xffff) << 7;
    const int off = offs[e], n_e = offs[e + 1] - off;
    const int by = blockIdx.y;   // 0..5

    __shared__ unsigned short SA[2][128 * 32];   // 16 KiB
    __shared__ unsigned short SB[2][256 * 32];   // 32 KiB

    const int tid = threadIdx.x;
    const int wid = tid >> 6, lane = tid & 63;
    const int l15 = lane & 15, kq = lane >> 4;
    const int wm = wid >> 2, wn = wid & 3;
    const int srow = tid >> 2;
    const int esw = (((tid & 3) ^ ((tid >> 3) & 3)) << 3);
    const int rk = ((kq ^ ((l15 >> 1) & 3)) << 3);

    int tok;
    { int s = m0 + srow; s = (s < n_e) ? s : (n_e - 1); tok = rows[off + s]; }
    size_t bB[2];
#pragma unroll
    for (int j = 0; j < 2; ++j)
        bB[j] = ((size_t)e * (2 * H_DIM) + by * 256 + j * 128 + srow) * D_DIM + esw;

    f32x4 acc[4][4];
#pragma unroll
    for (int m = 0; m < 4; ++m)
#pragma unroll
        for (int n = 0; n < 4; ++n)
#pragma unroll
            for (int r = 0; r < 4; ++r) acc[m][n][r] = 0.f;

    auto stage = [&](int buf, int k0) {
        const unsigned short* ga = xb + (size_t)tok * D_DIM + k0 + esw;
        __builtin_amdgcn_global_load_lds((gas_t)ga,
            (las_t)((char*)&SA[buf][0] + tid * 16), 16, 0, 0);
#pragma unroll
        for (int j = 0; j < 2; ++j) {
            const unsigned short* gb = W1T + bB[j] + k0;
            __builtin_amdgcn_global_load_lds((gas_t)gb,
                (las_t)((char*)&SB[buf][0] + j * 8192 + tid * 16), 16, 0, 0);
        }
    };

    stage(0, 0);
    stage(1, 32);
    int c = 0;
    const int NT = D_DIM / 32;   // 32
    for (int t = 0; t < NT; ++t) {
        if (t < NT - 1) asm volatile("s_waitcnt vmcnt(3)" ::: "memory");
        else            asm volatile("s_waitcnt vmcnt(0)" ::: "memory");
        __builtin_amdgcn_s_barrier();
        asm volatile("" ::: "memory");
        bf16x8 a[4], b[4];
#pragma unroll
        for (int m = 0; m < 4; ++m) {
            const int row = wm * 64 + m * 16 + l15;
            a[m] = __builtin_bit_cast(bf16x8, *reinterpret_cast<const u16x8*>(
                &SA[c][row * 32 + rk]));
        }
#pragma unroll
        for (int n = 0; n < 4; ++n) {
            const int row = wn * 64 + n * 16 + l15;
            b[n] = __builtin_bit_cast(bf16x8, *reinterpret_cast<const u16x8*>(
                &SB[c][row * 32 + rk]));
        }
#pragma unroll
        for (int m = 0; m < 4; ++m)
#pragma unroll
            for (int n = 0; n < 4; ++n)
                acc[m][n] = __builtin_amdgcn_mfma_f32_16x16x32_bf16(a[m], b[n], acc[m][n], 0, 0, 0);
        asm volatile("s_waitcnt lgkmcnt(0)" ::: "memory");
        __builtin_amdgcn_s_barrier();
        asm volatile("" ::: "memory");
        if (t + 2 < NT) stage(c, (t + 2) * 32);
        c ^= 1;
    }
    // epilogue: silu-gate; frag n<2 = v-cols, n>=2 = paired g-cols
#pragma unroll
    for (int m = 0; m < 4; ++m)
#pragma unroll
        for (int r = 0; r < 4; ++r) {
            const int row = wm * 64 + m * 16 + kq * 4 + r;
            if (m0 + row < n_e) {
#pragma unroll
                for (int nv = 0; nv < 2; ++nv) {
                    const int col = by * 128 + wn * 32 + nv * 16 + l15;
                    const float vv = acc[m][nv][r], gg = acc[m][2 + nv][r];
                    const float s = gg / (1.0f + __expf(-gg));
                    act[(size_t)(off + m0 + row) * H_DIM + col] = f2b(vv * s);
                }
            }
        }
}

// gemm2: slot_out bf16 stores (r8/r12-proven epilogue)
__global__ __launch_bounds__(512, 2) void k_gemm2_fast(
    const unsigned short* __restrict__ act, const unsigned short* __restrict__ W2T,
    const int* __restrict__ offs, const int* __restrict__ tiletab,
    const float* __restrict__ wslot, unsigned short* __restrict__ slot_out) {
    const int ti = (blockIdx.x & 7) * (NT128 / 8) + (blockIdx.x >> 3);
    const int tt = tiletab[ti];
    if (tt < 0) return;
    const int e = tt >> 16, m0 = (tt & 0xffff) << 7;
    const int off = offs[e], n_e = offs[e + 1] - off;
    const int by = blockIdx.y;   // 0..3

    __shared__ unsigned short SA[2][128 * 32];
    __shared__ unsigned short SB[2][256 * 32];

    const int tid = threadIdx.x;
    const int wid = tid >> 6, lane = tid & 63;
    const int l15 = lane & 15, kq = lane >> 4;
    const int wm = wid >> 2, wn = wid & 3;
    const int srow = tid >> 2;
    const int esw = (((tid & 3) ^ ((tid >> 3) & 3)) << 3);
    const int rk = ((kq ^ ((l15 >> 1) & 3)) << 3);

    int slotA;
    { int s = m0 + srow; s = (s < n_e) ? s : (n_e - 1); slotA = off + s; }
    size_t bB[2];
#pragma unroll
    for (int j = 0; j < 2; ++j)
        bB[j] = ((size_t)e * D_DIM + by * 256 + j * 128 + srow) * H_DIM + esw;

    f32x4 acc[4][4];
#pragma unroll
    for (int m = 0; m < 4; ++m)
#pragma unroll
        for (int n = 0; n < 4; ++n)
#pragma unroll
            for (int r = 0; r < 4; ++r) acc[m][n][r] = 0.f;

    auto stage = [&](int buf, int k0) {
        const unsigned short* ga = act + (size_t)slotA * H_DIM + k0 + esw;
        __builtin_amdgcn_global_load_lds((gas_t)ga,
            (las_t)((char*)&SA[buf][0] + tid * 16), 16, 0, 0);
#pragma unroll
        for (int j = 0; j < 2; ++j) {
            const unsigned short* gb = W2T + bB[j] + k0;
            __builtin_amdgcn_global_load_lds((gas_t)gb,
                (las_t)((char*)&SB[buf][0] + j * 8192 + tid * 16), 16, 0, 0);
        }
    };

    stage(0, 0);
    stage(1, 32);
    int c = 0;
    const int NT = H_DIM / 32;   // 24
    for (int t = 0; t < NT; ++t) {
        if (t < NT - 1) asm volatile("s_waitcnt vmcnt(3)" ::: "memory");
        else            asm volatile("s_waitcnt vmcnt(0)" ::: "memory");
        __builtin_amdgcn_s_barrier();
        asm volatile("" ::: "memory");
        bf16x8 a[4], b[4];
#pragma unroll
        for (int m = 0; m < 4; ++m) {
            const int row = wm * 64 + m * 16 + l15;
            a[m] = __builtin_bit_cast(bf16x8, *reinterpret_cast<const u16x8*>(
                &SA[c][row * 32 + rk]));
        }
#pragma unroll
        for (int n = 0; n < 4; ++n) {
            const int row = wn * 64 + n * 16 + l15;
            b[n] = __builtin_bit_cast(bf16x8, *reinterpret_cast<const u16x8*>(
                &SB[c][row * 32 + rk]));
        }
#pragma unroll
        for (int m = 0; m < 4; ++m)
#pragma unroll
            for (int n = 0; n < 4; ++n)
                acc[m][n] = __builtin_amdgcn_mfma_f32_16x16x32_bf16(a[m], b[n], acc[m][n], 0, 0, 0);
        asm volatile("s_waitcnt lgkmcnt(0)" ::: "memory");
        __builtin_amdgcn_s_barrier();
        asm volatile("" ::: "memory");
        if (t + 2 < NT) stage(c, (t + 2) * 32);
        c ^= 1;
    }
#pragma unroll
    for (int m = 0; m < 4; ++m)
#pragma unroll
        for (int r = 0; r < 4; ++r) {
            const int row = wm * 64 + m * 16 + kq * 4 + r;
            if (m0 + row < n_e) {
                const int slot = off + m0 + row;
                const float w = wslot[slot];
#pragma unroll
                for (int n = 0; n < 4; ++n) {
                    const int col = by * 256 + wn * 64 + n * 16 + l15;
                    slot_out[(size_t)slot * D_DIM + col] = f2b(w * acc[m][n][r]);
                }
            }
        }
}

// ================= FALLBACK PATH (small ws) =================
__global__ __launch_bounds__(256) void k_gather(const float* __restrict__ x,
                                                const int* __restrict__ rows,
                                                unsigned short* __restrict__ xg) {
    const int s = blockIdx.x, t = threadIdx.x;
    const int tok = rows[s];
    const float4 v = *reinterpret_cast<const float4*>(&x[(size_t)tok * D_DIM + t * 4]);
    ushort4 u;
    u.x = f2b(v.x); u.y = f2b(v.y); u.z = f2b(v.z); u.w = f2b(v.w);
    *reinterpret_cast<ushort4*>(&xg[(size_t)s * D_DIM + t * 4]) = u;
}

__global__ __launch_bounds__(256) void k_gemm1_fb(
    const unsigned short* __restrict__ xg, const float* __restrict__ W1,
    const int* __restrict__ offs, const int* __restrict__ tiletab,
    unsigned short* __restrict__ act) {
    const int tt = tiletab[blockIdx.x];
    if (tt < 0) return;
    const int e = tt >> 16, m0 = (tt & 0xffff) << 7;
    const int off = offs[e], n_e = offs[e + 1] - off;
    const int h0 = blockIdx.y * 64;

    __shared__ unsigned short Ab[128 * 64];
    __shared__ unsigned short Bb[128 * 66];

    const int tid = threadIdx.x;
    const int wid = tid >> 6, lane = tid & 63;
    const int l15 = lane & 15, kq = lane >> 4;

    f32x4 acc[2][8];
#pragma unroll
    for (int m = 0; m < 2; ++m)
#pragma unroll
        for (int n = 0; n < 8; ++n)
#pragma unroll
            for (int r = 0; r < 4; ++r) acc[m][n][r] = 0.f;

    for (int k0 = 0; k0 < D_DIM; k0 += 64) {
        __syncthreads();
#pragma unroll
        for (int j = 0; j < 4; ++j) {
            const int o = wid * 4096 + j * 1024 + lane * 16;
            const int row = o >> 7, kb = o & 127;
            int gr = off + m0 + row; gr = (gr < TK) ? gr : (TK - 1);
            const unsigned short* gp = xg + (size_t)gr * D_DIM + k0 + (kb >> 1);
            __builtin_amdgcn_global_load_lds((gas_t)gp,
                (las_t)((char*)Ab + wid * 4096 + j * 1024), 16, 0, 0);
        }
        {
            const float* W1e = W1 + (size_t)e * D_DIM * (2 * H_DIM);
#pragma unroll
            for (int i = 0; i < 8; ++i) {
                const int flat = tid + 256 * i;
                const int cg = flat & 31, kk = flat >> 5;
                const int cc = cg * 4;
                const int gc = (cc < 64) ? (h0 + cc) : (H_DIM + h0 + cc - 64);
                const float4 v = *reinterpret_cast<const float4*>(
                    &W1e[(size_t)(k0 + kk) * (2 * H_DIM) + gc]);
                Bb[(cc + 0) * 66 + kk] = f2b(v.x);
                Bb[(cc + 1) * 66 + kk] = f2b(v.y);
                Bb[(cc + 2) * 66 + kk] = f2b(v.z);
                Bb[(cc + 3) * 66 + kk] = f2b(v.w);
            }
        }
        __syncthreads();
#pragma unroll
        for (int ks = 0; ks < 2; ++ks) {
            bf16x8 a[2], b[8];
#pragma unroll
            for (int m = 0; m < 2; ++m)
                a[m] = __builtin_bit_cast(bf16x8, *reinterpret_cast<const u16x8*>(
                    &Ab[(wid * 32 + m * 16 + l15) * 64 + ks * 32 + kq * 8]));
#pragma unroll
            for (int n = 0; n < 8; ++n)
                b[n] = __builtin_bit_cast(bf16x8, *reinterpret_cast<const u16x8*>(
                    &Bb[(n * 16 + l15) * 66 + ks * 32 + kq * 8]));
#pragma unroll
            for (int m = 0; m < 2; ++m)
#pragma unroll
                for (int n = 0; n < 8; ++n)
                    acc[m][n] = __builtin_amdgcn_mfma_f32_16x16x32_bf16(a[m], b[n], acc[m][n], 0, 0, 0);
        }
    }
#pragma unroll
    for (int m = 0; m < 2; ++m)
#pragma unroll
        for (int n = 0; n < 4; ++n)
#pragma unroll
            for (int r = 0; r < 4; ++r) {
                const int row = wid * 32 + m * 16 + kq * 4 + r;
                if (m0 + row < n_e) {
                    const float vv = acc[m][n][r], gg = acc[m][n + 4][r];
                    const float s = gg / (1.0f + __expf(-gg));
                    act[(size_t)(off + m0 + row) * H_DIM + h0 + n * 16 + l15] = f2b(vv * s);
                }
            }
}

__global__ __launch_bounds__(256) void k_gemm2_fb(
    const unsigned short* __restrict__ act, const float* __restrict__ W2,
    const int* __restrict__ offs, const int* __restrict__ tiletab,
    const float* __restrict__ wslot, unsigned short* __restrict__ slot_out,
    float* __restrict__ y, const int* __restrict__ rows, int atomic_mode) {
    const int tt = tiletab[blockIdx.x];
    if (tt < 0) return;
    const int e = tt >> 16, m0 = (tt & 0xffff) << 7;
    const int off = offs[e], n_e = offs[e + 1] - off;
    const int n0 = blockIdx.y * 64;

    __shared__ unsigned short Ab[128 * 64];
    __shared__ unsigned short Bb[64 * 66];

    const int tid = threadIdx.x;
    const int wid = tid >> 6, lane = tid & 63;
    const int l15 = lane & 15, kq = lane >> 4;

    f32x4 acc[2][4];
#pragma unroll
    for (int m = 0; m < 2; ++m)
#pragma unroll
        for (int n = 0; n < 4; ++n)
#pragma unroll
            for (int r = 0; r < 4; ++r) acc[m][n][r] = 0.f;

    for (int k0 = 0; k0 < H_DIM; k0 += 64) {
        __syncthreads();
#pragma unroll
        for (int j = 0; j < 4; ++j) {
            const int o = wid * 4096 + j * 1024 + lane * 16;
            const int row = o >> 7, kb = o & 127;
            int gr = off + m0 + row; gr = (gr < TK) ? gr : (TK - 1);
            const unsigned short* gp = act + (size_t)gr * H_DIM + k0 + (kb >> 1);
            __builtin_amdgcn_global_load_lds((gas_t)gp,
                (las_t)((char*)Ab + wid * 4096 + j * 1024), 16, 0, 0);
        }
        {
            const float* W2e = W2 + (size_t)e * H_DIM * D_DIM;
#pragma unroll
            for (int i = 0; i < 4; ++i) {
                const int flat = tid + 256 * i;
                const int cg = flat & 15, kk = flat >> 4;
                const int cc = cg * 4;
                const float4 v = *reinterpret_cast<const float4*>(
                    &W2e[(size_t)(k0 + kk) * D_DIM + n0 + cc]);
                Bb[(cc + 0) * 66 + kk] = f2b(v.x);
                Bb[(cc + 1) * 66 + kk] = f2b(v.y);
                Bb[(cc + 2) * 66 + kk] = f2b(v.z);
                Bb[(cc + 3) * 66 + kk] = f2b(v.w);
            }
        }
        __syncthreads();
#pragma unroll
        for (int ks = 0; ks < 2; ++ks) {
            bf16x8 a[2], b[4];
#pragma unroll
            for (int m = 0; m < 2; ++m)
                a[m] = __builtin_bit_cast(bf16x8, *reinterpret_cast<const u16x8*>(
                    &Ab[(wid * 32 + m * 16 + l15) * 64 + ks * 32 + kq * 8]));
#pragma unroll
            for (int n = 0; n < 4; ++n)
                b[n] = __builtin_bit_cast(bf16x8, *reinterpret_cast<const u16x8*>(
                    &Bb[(n * 16 + l15) * 66 + ks * 32 + kq * 8]));
#pragma unroll
            for (int m = 0; m < 2; ++m)
#pragma unroll
                for (int n = 0; n < 4; ++n)
                    acc[m][n] = __builtin_amdgcn_mfma_f32_16x16x32_bf16(a[m], b[n], acc[m][n], 0, 0, 0);
        }
    }
#pragma unroll
    for (int m = 0; m < 2; ++m)
#pragma unroll
        for (int r = 0; r < 4; ++r) {
            const int row = wid * 32 + m * 16 + kq * 4 + r;
            if (m0 + row < n_e) {
                const int slot = off + m0 + row;
                const float w = wslot[slot];
#pragma unroll
                for (int n = 0; n < 4; ++n) {
                    const float o = w * acc[m][n][r];
                    if (atomic_mode)
                        atomicAdd(&y[(size_t)rows[slot] * D_DIM + n0 + n * 16 + l15], o);
                    else
                        slot_out[(size_t)slot * D_DIM + n0 + n * 16 + l15] = f2b(o);
                }
            }
        }
}

// ---------------- combine: y[t] = out[slot(t,0)] + out[slot(t,1)] ----------------
__global__ __launch_bounds__(128) void k_combine(
    const unsigned short* __restrict__ slot_out, const int* __restrict__ slot_of,
    float* __restrict__ y) {
    const int t = blockIdx.x;
    const int d = threadIdx.x * 8;
    const int s0 = slot_of[2 * t], s1 = slot_of[2 * t + 1];
    const u16x8 a = *reinterpret_cast<const u16x8*>(&slot_out[(size_t)s0 * D_DIM + d]);
    const u16x8 b = *reinterpret_cast<const u16x8*>(&slot_out[(size_t)s1 * D_DIM + d]);
    float4 r0, r1;
    r0.x = b2f(a[0]) + b2f(b[0]); r0.y = b2f(a[1]) + b2f(b[1]);
    r0.z = b2f(a[2]) + b2f(b[2]); r0.w = b2f(a[3]) + b2f(b[3]);
    r1.x = b2f(a[4]) + b2f(b[4]); r1.y = b2f(a[5]) + b2f(b[5]);
    r1.z = b2f(a[6]) + b2f(b[6]); r1.w = b2f(a[7]) + b2f(b[7]);
    *reinterpret_cast<float4*>(&y[(size_t)t * D_DIM + d]) = r0;
    *reinterpret_cast<float4*>(&y[(size_t)t * D_DIM + d + 4]) = r1;
}

extern "C" void kernel_launch(void* const* d_in, const int* in_sizes, int n_in,
                              void* d_out, int out_size, void* d_ws, size_t ws_size,
                              hipStream_t stream) {
    const float* x = (const float*)d_in[0];
    const float* wts = (const float*)d_in[1];
    const int* idx = (const int*)d_in[2];
    const float* W1 = (const float*)d_in[4];
    const float* W2 = (const float*)d_in[5];
    float* y = (float*)d_out;

    char* ws = (char*)d_ws;
    int* offs = (int*)(ws + 128);
    int* tiletab = (int*)(ws + 320);
    int* rows = (int*)(ws + 2048);
    float* wslot = (float*)(ws + 2048 + (size_t)TK * 4);
    int* slot_of = (int*)(ws + 2048 + (size_t)TK * 8);
    const size_t OFF_XG = 2048 + (size_t)TK * 12;
    unsigned short* xg = (unsigned short*)(ws + OFF_XG);
    unsigned short* xb = xg;
    const size_t OFF_ACT = OFF_XG + (size_t)TK * D_DIM * 2;
    unsigned short* act = (unsigned short*)(ws + OFF_ACT);
    const size_t OFF_SO = OFF_ACT + (size_t)TK * H_DIM * 2;
    unsigned short* slot_out = (unsigned short*)(ws + OFF_SO);
    const size_t MID_END = OFF_SO + (size_t)TK * D_DIM * 2;
    const size_t OFF_W1T = MID_END;
    unsigned short* W1T = (unsigned short*)(ws + OFF_W1T);
    const size_t OFF_W2T = OFF_W1T + (size_t)E_EXP * 2 * H_DIM * D_DIM * 2;
    unsigned short* W2T = (unsigned short*)(ws + OFF_W2T);
    const size_t FULL_END = OFF_W2T + (size_t)E_EXP * D_DIM * H_DIM * 2;

    const int full = (ws_size >= FULL_END) ? 1 : 0;
    const int atomic_mode = (!full && ws_size < MID_END) ? 1 : 0;

    if (full) {
        k_preproute<<<PRB_TOT, 512, 0, stream>>>(x, W1, W2, idx, wts, xb, W1T, W2T,
                                                 offs, tiletab, rows, wslot, slot_of);
        dim3 g1(NT128, H_DIM / 128);
        k_gemm1_fast<<<g1, 512, 0, stream>>>(xb, W1T, offs, tiletab, rows, act);
        dim3 g2(NT128, D_DIM / 256);
        k_gemm2_fast<<<g2, 512, 0, stream>>>(act, W2T, offs, tiletab, wslot, slot_out);
        k_combine<<<T_TOK, 128, 0, stream>>>(slot_out, slot_of, y);
    } else {
        k_route<<<1, 512, 0, stream>>>(idx, wts, offs, tiletab, rows, wslot, slot_of);
        k_gather<<<TK, 256, 0, stream>>>(x, rows, xg);
        dim3 g1(NT128, H_DIM / 64);
        k_gemm1_fb<<<g1, 256, 0, stream>>>(xg, W1, offs, tiletab, act);
        if (atomic_mode) hipMemsetAsync(y, 0, (size_t)out_size * 4, stream);
        dim3 g2(NT128, D_DIM / 64);
        k_gemm2_fb<<<g2, 256, 0, stream>>>(act, W2, offs, tiletab, wslot, slot_out, y, rows, atomic_mode);
        if (!atomic_mode)
            k_combine<<<T_TOK, 128, 0, stream>>>(slot_out, slot_of, y);
    }
}